// Round 1
// baseline (409.695 us; speedup 1.0000x reference)
//
#include <hip/hip_runtime.h>
#include <cstdint>
#include <cstddef>

// Problem constants (fixed by reference)
#define B_    4
#define S_    4096
#define DIN_  2048
#define DOUT_ 2048
#define R_    16
#define E_    12
// MULTIPLIER * SCALE == 1.0 — folded away.

typedef __bf16 bf16x8 __attribute__((ext_vector_type(8)));
typedef float  floatx4 __attribute__((ext_vector_type(4)));

__device__ __forceinline__ unsigned short f2bf(float f) {
  unsigned int u = __builtin_bit_cast(unsigned int, f);
  u += 0x7fffu + ((u >> 16) & 1u);   // round-to-nearest-even
  return (unsigned short)(u >> 16);
}

__device__ __forceinline__ void async_copy16(const void* g, void* l) {
  __builtin_amdgcn_global_load_lds(
      (const __attribute__((address_space(1))) void*)g,
      (__attribute__((address_space(3))) void*)l,
      16, 0, 0);
}

// ---------------------------------------------------------------------------
// Kernel 1: x fp32 -> bf16 (memory-bound pass)
// ---------------------------------------------------------------------------
__global__ __launch_bounds__(256) void cvt_bf16_kernel(const float* __restrict__ x,
                                                       unsigned short* __restrict__ xb) {
  size_t idx = (size_t)blockIdx.x * 256 + threadIdx.x;
  float4 v = ((const float4*)x)[idx];
  uint2 o;
  o.x = (unsigned)f2bf(v.x) | ((unsigned)f2bf(v.y) << 16);
  o.y = (unsigned)f2bf(v.z) | ((unsigned)f2bf(v.w) << 16);
  ((uint2*)xb)[idx] = o;
}

// ---------------------------------------------------------------------------
// Kernel 2: W_eff[b] = W_org + (gate[b] . W_up) @ W_down   -> bf16
// Block: 256 threads handles 32 o-rows x 1024 i-cols.
// W_down slice (16 r x 4 i) lives in registers; combined staged in LDS.
// ---------------------------------------------------------------------------
__global__ __launch_bounds__(256) void weff_kernel(const float* __restrict__ gate,
                                                   const float* __restrict__ W_org,
                                                   const float* __restrict__ W_down,
                                                   const float* __restrict__ W_up,
                                                   unsigned short* __restrict__ W_eff) {
  const int b   = blockIdx.y;
  const int og  = blockIdx.x >> 1;   // 64 groups of 32 o-rows
  const int ig  = blockIdx.x & 1;    // 2 groups of 1024 i-cols
  const int tid = threadIdx.x;

  __shared__ float comb[32 * 16];    // combined[o_local][r]

  // Phase 1: combined[b, o, r] = sum_e gate[b,e] * W_up[e,o,r]
  for (int e0 = tid; e0 < 32 * 16; e0 += 256) {
    const int ol = e0 >> 4, r = e0 & 15;
    const int o = og * 32 + ol;
    float s = 0.f;
#pragma unroll
    for (int e = 0; e < E_; ++e)
      s += gate[b * E_ + e] * W_up[((size_t)e * DOUT_ + o) * R_ + r];
    comb[e0] = s;
  }
  __syncthreads();

  const int i = ig * 1024 + tid * 4;
  float4 wd[R_];
#pragma unroll
  for (int r = 0; r < R_; ++r)
    wd[r] = *(const float4*)&W_down[(size_t)r * DIN_ + i];

  for (int ol = 0; ol < 32; ++ol) {
    const int o = og * 32 + ol;
    float4 acc = *(const float4*)&W_org[(size_t)o * DIN_ + i];
#pragma unroll
    for (int r = 0; r < R_; ++r) {
      const float g = comb[ol * 16 + r];
      acc.x += g * wd[r].x;
      acc.y += g * wd[r].y;
      acc.z += g * wd[r].z;
      acc.w += g * wd[r].w;
    }
    uint2 pk;
    pk.x = (unsigned)f2bf(acc.x) | ((unsigned)f2bf(acc.y) << 16);
    pk.y = (unsigned)f2bf(acc.z) | ((unsigned)f2bf(acc.w) << 16);
    *(uint2*)&W_eff[((size_t)b * DOUT_ + o) * DIN_ + i] = pk;
  }
}

// ---------------------------------------------------------------------------
// Kernel 3: per-batch NT GEMM  C[b] = A[b] @ Bw[b]^T  (bf16 in, fp32 out)
// m97 structure: 128x128 tile, BK=64, global_load_lds width 16, 2-barrier
// K-loop, 4 waves x (4x4 of 16x16x32 MFMA). XOR swizzle (chunk ^= row&7)
// applied on the GLOBAL address so LDS dest stays base+lane*16, while
// ds_read_b128 fragment reads spread over all 32 banks (2-way = free).
// ---------------------------------------------------------------------------
__global__ __launch_bounds__(256) void gemm_kernel(const unsigned short* __restrict__ A,
                                                   const unsigned short* __restrict__ Bw,
                                                   float* __restrict__ C) {
  constexpr int K = DIN_, N = DOUT_;
  __shared__ unsigned short lds[2 * 128 * 64];   // 32 KiB: A-tile then B-tile
  unsigned short* ldsA = lds;
  unsigned short* ldsB = lds + 128 * 64;

  const int tid  = threadIdx.x;
  const int lane = tid & 63;
  const int wave = tid >> 6;
  const int wm   = wave >> 1;      // wave row (0..1)
  const int wn   = wave & 1;       // wave col (0..1)
  const int q    = lane >> 4;      // quad index 0..3
  const int mrow = lane & 15;

  const int mBase = blockIdx.y * 128;
  const int nBase = blockIdx.x * 128;
  const int batch = blockIdx.z;

  const unsigned short* Ab = A  + (size_t)batch * S_ * K;
  const unsigned short* Bb = Bw + (size_t)batch * N  * K;

  floatx4 acc[4][4] = {};

  for (int kt = 0; kt < K / 64; ++kt) {
    const int k0 = kt * 64;
    // ---- stage A and B tiles (128 rows x 64 bf16 each) ----
#pragma unroll
    for (int is = 0; is < 4; ++is) {
      const int p    = is * 4096 + wave * 1024 + lane * 16;  // byte pos in tile
      const int row  = p >> 7;                               // tile row
      const int slot = (p >> 4) & 7;                         // 16B slot in row
      const int ch   = slot ^ (row & 7);                     // swizzled source chunk
      const unsigned short* ga = Ab + (size_t)(mBase + row) * K + k0 + ch * 8;
      const unsigned short* gb = Bb + (size_t)(nBase + row) * K + k0 + ch * 8;
      async_copy16(ga, (char*)ldsA + p);
      async_copy16(gb, (char*)ldsB + p);
    }
    __syncthreads();   // drains vmcnt(0) + barrier (compiler-inserted)

    // ---- compute: 2 k-steps of 16x16x32, 16 MFMA each ----
#pragma unroll
    for (int kk = 0; kk < 2; ++kk) {
      bf16x8 af[4], bfr[4];
#pragma unroll
      for (int mt = 0; mt < 4; ++mt) {
        const int r = wm * 64 + mt * 16 + mrow;
        const int c = kk * 4 + q;
        af[mt] = *(const bf16x8*)&ldsA[r * 64 + ((c ^ (r & 7)) << 3)];
      }
#pragma unroll
      for (int nt = 0; nt < 4; ++nt) {
        const int r = wn * 64 + nt * 16 + mrow;
        const int c = kk * 4 + q;
        bfr[nt] = *(const bf16x8*)&ldsB[r * 64 + ((c ^ (r & 7)) << 3)];
      }
#pragma unroll
      for (int mt = 0; mt < 4; ++mt)
#pragma unroll
        for (int nt = 0; nt < 4; ++nt)
          acc[mt][nt] = __builtin_amdgcn_mfma_f32_16x16x32_bf16(af[mt], bfr[nt],
                                                                acc[mt][nt], 0, 0, 0);
    }
    __syncthreads();   // protect LDS before next stage overwrites
  }

  // ---- epilogue: C/D layout col=lane&15, row=(lane>>4)*4+reg ----
#pragma unroll
  for (int mt = 0; mt < 4; ++mt) {
#pragma unroll
    for (int nt = 0; nt < 4; ++nt) {
      const int gc  = nBase + wn * 64 + nt * 16 + mrow;
      const int gr0 = mBase + wm * 64 + mt * 16 + q * 4;
#pragma unroll
      for (int rg = 0; rg < 4; ++rg)
        C[((size_t)batch * S_ + gr0 + rg) * N + gc] = acc[mt][nt][rg];
    }
  }
}

// ---------------------------------------------------------------------------
extern "C" void kernel_launch(void* const* d_in, const int* in_sizes, int n_in,
                              void* d_out, int out_size, void* d_ws, size_t ws_size,
                              hipStream_t stream) {
  const float* x      = (const float*)d_in[0];
  const float* gate   = (const float*)d_in[1];
  const float* W_org  = (const float*)d_in[2];
  const float* W_down = (const float*)d_in[3];
  const float* W_up   = (const float*)d_in[4];
  float* out = (float*)d_out;

  // workspace: x_bf16 (67,108,864 B) then W_eff bf16 (33,554,432 B)
  unsigned short* xb   = (unsigned short*)d_ws;
  unsigned short* weff = xb + (size_t)B_ * S_ * DIN_;

  // 1) x -> bf16
  cvt_bf16_kernel<<<(B_ * S_ * DIN_) / 4 / 256, 256, 0, stream>>>(x, xb);

  // 2) W_eff[b] = W_org + combined[b] @ W_down   (bf16)
  weff_kernel<<<dim3(128, B_), 256, 0, stream>>>(gate, W_org, W_down, W_up, weff);

  // 3) out[b] = x[b] @ W_eff[b]^T   (fp32 out)
  gemm_kernel<<<dim3(DOUT_ / 128, S_ / 128, B_), 256, 0, stream>>>(xb, weff, out);
}